// Round 1
// baseline (10714.560 us; speedup 1.0000x reference)
//
#include <hip/hip_runtime.h>
#include <math.h>

// Problem constants (from reference setup_inputs):
// B=8, T=64, Cin=64, L=256, F=128, K=5 (SAME pad=2), fp32 throughout.
#define B_SZ 8
#define T_SZ 64
#define CIN 64
#define L_LEN 256
#define F_CH 128
#define K_W 5
#define LTILE 64          // lanes of a wave cover 64 consecutive l
#define CH_CHUNK 64       // channels staged to LDS per chunk
#define PADL (LTILE + 4)  // +4 halo for K=5

__device__ __forceinline__ float sigmoid_f(float x) {
    return 1.0f / (1.0f + __expf(-x));
}
__device__ __forceinline__ float tanh_f(float x) {
    // numerically safe tanh via exp of -2|x| (avoids inf/inf NaN)
    float a = fabsf(x);
    float e = __expf(-2.0f * a);
    float t = (1.0f - e) / (1.0f + e);
    return copysignf(t, x);
}

// One ConvLSTM timestep for one layer.
// grid = (L/64, B, F/4); block = 256 (4 waves). Each wave owns ONE f
// (wave-uniform via readfirstlane -> weights become scalar s_loads),
// lane = l within the 64-wide l-tile. Each thread computes all 4 gates.
template<int C0, int CTOT>
__global__ __launch_bounds__(256)
void convlstm_step(const float* __restrict__ in0, int stride_in0_b,
                   const float* __restrict__ hprev,   // [B,F,L]
                   const float* __restrict__ W,       // [4F, CTOT, K]
                   const float* __restrict__ bias,    // [4F]
                   const float* __restrict__ c_in,    // [B,F,L]
                   float* __restrict__ c_out,         // [B,F,L]
                   float* __restrict__ h_out)         // [B,F,L] slice
{
    __shared__ float sh[CH_CHUNK * PADL];

    const int tid  = threadIdx.x;
    const int lane = tid & 63;
    const int wave = tid >> 6;
    const int l0   = blockIdx.x * LTILE;
    const int b    = blockIdx.y;
    // wave-uniform f => scalar weight loads
    const int f    = __builtin_amdgcn_readfirstlane(blockIdx.z * 4 + wave);

    float acc_i = 0.f, acc_f = 0.f, acc_o = 0.f, acc_g = 0.f;

    constexpr int NCHUNK = CTOT / CH_CHUNK;
    for (int ch = 0; ch < NCHUNK; ++ch) {
        const int cbase = ch * CH_CHUNK;
        // CH_CHUNK=64 divides both C0 (64 or 128) and F, so each chunk
        // comes wholly from one source tensor.
        const float* src = (cbase < C0)
            ? (in0 + b * stride_in0_b + cbase * L_LEN)
            : (hprev + b * (F_CH * L_LEN) + (cbase - C0) * L_LEN);

        __syncthreads();  // protect prior chunk's LDS reads
        for (int i = tid; i < CH_CHUNK * PADL; i += 256) {
            int cl = i / PADL;
            int p  = i - cl * PADL;
            int gl = l0 + p - 2;
            float v = 0.f;
            if (gl >= 0 && gl < L_LEN) v = src[cl * L_LEN + gl];
            sh[i] = v;
        }
        __syncthreads();

        const float* wi = W + ((0 * F_CH + f) * CTOT + cbase) * K_W;
        const float* wf = W + ((1 * F_CH + f) * CTOT + cbase) * K_W;
        const float* wo = W + ((2 * F_CH + f) * CTOT + cbase) * K_W;
        const float* wg = W + ((3 * F_CH + f) * CTOT + cbase) * K_W;

        #pragma unroll 4
        for (int cl = 0; cl < CH_CHUNK; ++cl) {
            const float* row = sh + cl * PADL + lane;
            float x0 = row[0];
            float x1 = row[1];
            float x2 = row[2];
            float x3 = row[3];
            float x4 = row[4];
            const float* pi = wi + cl * K_W;
            const float* pf = wf + cl * K_W;
            const float* po = wo + cl * K_W;
            const float* pg = wg + cl * K_W;
            acc_i = fmaf(pi[0], x0, acc_i);
            acc_i = fmaf(pi[1], x1, acc_i);
            acc_i = fmaf(pi[2], x2, acc_i);
            acc_i = fmaf(pi[3], x3, acc_i);
            acc_i = fmaf(pi[4], x4, acc_i);
            acc_f = fmaf(pf[0], x0, acc_f);
            acc_f = fmaf(pf[1], x1, acc_f);
            acc_f = fmaf(pf[2], x2, acc_f);
            acc_f = fmaf(pf[3], x3, acc_f);
            acc_f = fmaf(pf[4], x4, acc_f);
            acc_o = fmaf(po[0], x0, acc_o);
            acc_o = fmaf(po[1], x1, acc_o);
            acc_o = fmaf(po[2], x2, acc_o);
            acc_o = fmaf(po[3], x3, acc_o);
            acc_o = fmaf(po[4], x4, acc_o);
            acc_g = fmaf(pg[0], x0, acc_g);
            acc_g = fmaf(pg[1], x1, acc_g);
            acc_g = fmaf(pg[2], x2, acc_g);
            acc_g = fmaf(pg[3], x3, acc_g);
            acc_g = fmaf(pg[4], x4, acc_g);
        }
    }

    // epilogue: gates + state update
    const float bi = bias[0 * F_CH + f];
    const float bf = bias[1 * F_CH + f];
    const float bo = bias[2 * F_CH + f];
    const float bg = bias[3 * F_CH + f];

    float gi = sigmoid_f(acc_i + bi);
    float gf = sigmoid_f(acc_f + bf);
    float go = sigmoid_f(acc_o + bo);
    float gg = tanh_f(acc_g + bg);

    const int idx = (b * F_CH + f) * L_LEN + (l0 + lane);
    float cprev = c_in[idx];
    float cn = gf * cprev + gi * gg;
    float hn = go * tanh_f(cn);
    c_out[idx] = cn;
    h_out[idx] = hn;
}

extern "C" void kernel_launch(void* const* d_in, const int* in_sizes, int n_in,
                              void* d_out, int out_size, void* d_ws, size_t ws_size,
                              hipStream_t stream)
{
    const float* x  = (const float*)d_in[0];  // [B,T,Cin,L]
    const float* W0 = (const float*)d_in[1];  // [512,192,5]
    const float* b0 = (const float*)d_in[2];  // [512]
    const float* W1 = (const float*)d_in[3];  // [512,256,5]
    const float* b1 = (const float*)d_in[4];  // [512]
    const float* h0 = (const float*)d_in[5];  // [B,F,L]
    const float* c0 = (const float*)d_in[6];
    const float* h1 = (const float*)d_in[7];
    const float* c1 = (const float*)d_in[8];
    float* out = (float*)d_out;               // [T,B,F,L]

    const int S = B_SZ * F_CH * L_LEN;        // 262144 elems per [B,F,L] slab
    float* ws    = (float*)d_ws;
    float* hs0_a = ws;                        // layer0 h state / layer1 input, ping
    float* hs0_b = ws + S;                    // pong
    float* c0w   = ws + 2 * S;                // layer0 c state (in-place after t=0)
    float* c1w   = ws + 3 * S;                // layer1 c state

    dim3 grid(L_LEN / LTILE, B_SZ, F_CH / 4); // (4, 8, 32) = 1024 blocks
    dim3 block(256);

    for (int t = 0; t < T_SZ; ++t) {
        // ---- layer 0 ----
        const float* hprev0 = (t == 0) ? h0 : ((t & 1) ? hs0_a : hs0_b);
        float*       hout0  = (t & 1) ? hs0_b : hs0_a;
        const float* cin0   = (t == 0) ? c0 : c0w;
        convlstm_step<CIN, CIN + F_CH><<<grid, block, 0, stream>>>(
            x + t * CIN * L_LEN, T_SZ * CIN * L_LEN,
            hprev0, W0, b0, cin0, c0w, hout0);

        // ---- layer 1 ---- (h1 recurrent state lives in d_out[t-1])
        const float* hprev1 = (t == 0) ? h1 : (out + (size_t)(t - 1) * S);
        const float* cin1   = (t == 0) ? c1 : c1w;
        convlstm_step<F_CH, 2 * F_CH><<<grid, block, 0, stream>>>(
            hout0, F_CH * L_LEN,
            hprev1, W1, b1, cin1, c1w, out + (size_t)t * S);
    }
}